// Round 6
// baseline (176.497 us; speedup 1.0000x reference)
//
#include <hip/hip_runtime.h>
#include <math.h>

#define NV 4
#define NB 2
#define NC 32
#define ND 32
#define NH 128
#define NW 160
#define NG 8
#define HW (NH*NW)
#define NPIX (NB*NH*NW)
#define FEATSZ (NV*NB*HW*NC)

// ---------------------------------------------------------------------------
// proj setup (unchanged)
// ---------------------------------------------------------------------------
__global__ void proj_setup_kernel(const float* __restrict__ proj,
                                  float* __restrict__ pw) {
    int t = blockIdx.x * blockDim.x + threadIdx.x;
    if (t >= NB * NV) return;
    int b = t / NV, v = t % NV;
    const float* Eref = proj + ((b*(NV+1) + 0)*2 + 0)*16;
    const float* Kref = proj + ((b*(NV+1) + 0)*2 + 1)*16;
    const float* Esrc = proj + ((b*(NV+1) + (v+1))*2 + 0)*16;
    const float* Ksrc = proj + ((b*(NV+1) + (v+1))*2 + 1)*16;
    float Mr[12], Ms[12];
    for (int i = 0; i < 3; ++i)
        for (int j = 0; j < 4; ++j) {
            float sr = 0.f, ss = 0.f;
            for (int k = 0; k < 3; ++k) {
                sr += Kref[i*4+k] * Eref[k*4+j];
                ss += Ksrc[i*4+k] * Esrc[k*4+j];
            }
            Mr[i*4+j] = sr; Ms[i*4+j] = ss;
        }
    double A[9], a[3];
    for (int i = 0; i < 3; ++i) {
        for (int j = 0; j < 3; ++j) A[i*3+j] = (double)Mr[i*4+j];
        a[i] = (double)Mr[i*4+3];
    }
    double c00 = A[4]*A[8]-A[5]*A[7];
    double c01 = A[5]*A[6]-A[3]*A[8];
    double c02 = A[3]*A[7]-A[4]*A[6];
    double det = A[0]*c00 + A[1]*c01 + A[2]*c02;
    double id  = 1.0/det;
    double Ai[9];
    Ai[0]=c00*id;                 Ai[1]=(A[2]*A[7]-A[1]*A[8])*id; Ai[2]=(A[1]*A[5]-A[2]*A[4])*id;
    Ai[3]=c01*id;                 Ai[4]=(A[0]*A[8]-A[2]*A[6])*id; Ai[5]=(A[2]*A[3]-A[0]*A[5])*id;
    Ai[6]=c02*id;                 Ai[7]=(A[1]*A[6]-A[0]*A[7])*id; Ai[8]=(A[0]*A[4]-A[1]*A[3])*id;
    double R[9], T[3];
    for (int i = 0; i < 3; ++i)
        for (int j = 0; j < 3; ++j) {
            double s = 0.0;
            for (int k = 0; k < 3; ++k) s += (double)Ms[i*4+k] * Ai[k*3+j];
            R[i*3+j] = s;
        }
    for (int i = 0; i < 3; ++i) {
        double s = (double)Ms[i*4+3];
        for (int k = 0; k < 3; ++k) s -= R[i*3+k]*a[k];
        T[i] = s;
    }
    float* o = pw + (b*NV + v)*12;
    for (int i = 0; i < 9; ++i) o[i]   = (float)R[i];
    for (int i = 0; i < 3; ++i) o[9+i] = (float)T[i];
}

// ---------------------------------------------------------------------------
// LDS-tiled transpose: [vb][c][hw] -> [vb][hw][c] (unchanged)
// ---------------------------------------------------------------------------
__global__ __launch_bounds__(256) void transpose_kernel(
    const float* __restrict__ in, float* __restrict__ out) {
    __shared__ float lds[NC][65];
    int vb = blockIdx.y;
    int hwbase = blockIdx.x * 64;
    int t = threadIdx.x;
    #pragma unroll
    for (int r = 0; r < 8; ++r) {
        int c  = (t >> 6) + r*4;
        int hw = t & 63;
        lds[c][hw] = in[(vb*NC + c)*HW + hwbase + hw];
    }
    __syncthreads();
    #pragma unroll
    for (int r = 0; r < 8; ++r) {
        int c  = t & 31;
        int hw = (t >> 5) + r*8;
        out[((size_t)vb*HW + hwbase + hw)*NC + c] = lds[c][hw];
    }
}

// ---------------------------------------------------------------------------
// Main: wave = one pixel = 2 half-waves x 32 depths. Half hi owns views
// {2hi, 2hi+1}; per-thread serial chain is 2 views instead of 4. Cross-half
// combine fetches the other pair's (cw,t) via shfl_xor(32) and evaluates the
// view-accumulation in exact reference order -> bit-identical results.
// ---------------------------------------------------------------------------
__global__ __launch_bounds__(256) void mvs_kernel_t(
    const float* __restrict__ refT,
    const float* __restrict__ srcT,
    const float* __restrict__ depth_hypo,
    const float* __restrict__ w_reg,
    const float* __restrict__ pw,
    float* __restrict__ out)
{
    int tid = blockIdx.x * 256 + threadIdx.x;
    int lane = threadIdx.x & 63;
    int d  = lane & 31;
    int hi = lane >> 5;            // 0: views 0,1   1: views 2,3
    int p  = tid >> 6;
    if (p >= NPIX) return;
    int w = p % NW;
    int h = (p / NW) % NH;
    int b = p / (NW*NH);
    float xf = (float)w, yf = (float)h;
    float depth = depth_hypo[((b*ND + d)*NH + h)*NW + w];

    float wr[NG];
    #pragma unroll
    for (int g = 0; g < NG; ++g) wr[g] = w_reg[g];

    float sv[2], tv[2];

    #pragma unroll
    for (int vv = 0; vv < 2; ++vv) {
        int v = hi*2 + vv;
        const float* RT = pw + (b*NV + v)*12;
        double dd  = (double)depth;
        double px_ = ((double)RT[0]*(double)xf + (double)RT[1]*(double)yf + (double)RT[2])*dd + (double)RT[9];
        double py_ = ((double)RT[3]*(double)xf + (double)RT[4]*(double)yf + (double)RT[5])*dd + (double)RT[10];
        double pz_ = ((double)RT[6]*(double)xf + (double)RT[7]*(double)yf + (double)RT[8])*dd + (double)RT[11];
        if (pz_ == 0.0) pz_ = 1e-9;
        double iz  = 1.0 / pz_;
        double pxd = px_*iz, pyd = py_*iz;
        double x0d = floor(pxd), y0d = floor(pyd);
        int x0i = (int)x0d, y0i = (int)y0d;
        int x1i = x0i + 1,  y1i = y0i + 1;
        float wx = (float)(pxd - x0d), wy = (float)(pyd - y0d);

        float vx0 = (x0i >= 0 && x0i < NW) ? 1.f : 0.f;
        float vx1 = (x1i >= 0 && x1i < NW) ? 1.f : 0.f;
        float vy0 = (y0i >= 0 && y0i < NH) ? 1.f : 0.f;
        float vy1 = (y1i >= 0 && y1i < NH) ? 1.f : 0.f;
        float w00 = (1.f-wx)*(1.f-wy) * vx0*vy0;
        float w01 = wx*(1.f-wy)       * vx1*vy0;
        float w10 = (1.f-wx)*wy       * vx0*vy1;
        float w11 = wx*wy             * vx1*vy1;
        int xc0 = min(max(x0i,0),NW-1), xc1 = min(max(x1i,0),NW-1);
        int yc0 = min(max(y0i,0),NH-1), yc1 = min(max(y1i,0),NH-1);
        int i00 = yc0*NW+xc0, i01 = yc0*NW+xc1;
        int i10 = yc1*NW+xc0, i11 = yc1*NW+xc1;

        int vb = v*NB + b;
        const float4* s00 = (const float4*)(srcT + ((size_t)vb*HW + i00)*NC);
        const float4* s01 = (const float4*)(srcT + ((size_t)vb*HW + i01)*NC);
        const float4* s10 = (const float4*)(srcT + ((size_t)vb*HW + i10)*NC);
        const float4* s11 = (const float4*)(srcT + ((size_t)vb*HW + i11)*NC);
        const float4* rr  = (const float4*)(refT + ((size_t)vb*HW + h*NW+w)*NC);

        float s = 0.f, t = 0.f;
        #pragma unroll
        for (int j = 0; j < NG; ++j) {
            float4 a00 = s00[j], a01 = s01[j], a10 = s10[j], a11 = s11[j];
            float4 rf  = rr[j];
            float acc = 0.f;
            float f0 = w00*a00.x + w01*a01.x + w10*a10.x + w11*a11.x;
            acc += f0*rf.x;
            float f1 = w00*a00.y + w01*a01.y + w10*a10.y + w11*a11.y;
            acc += f1*rf.y;
            float f2 = w00*a00.z + w01*a01.z + w10*a10.z + w11*a11.z;
            acc += f2*rf.z;
            float f3 = w00*a00.w + w01*a01.w + w10*a10.w + w11*a11.w;
            acc += f3*rf.w;
            float cf = 0.25f*acc;
            s += cf;
            t += cf*wr[j];
        }
        sv[vv] = s; tv[vv] = t;
    }

    // ---- per-view softmax over depths, within the 32-lane half (2-way ILP) ----
    float mv0 = sv[0], mv1 = sv[1];
    #pragma unroll
    for (int mask = 1; mask < 32; mask <<= 1) {
        mv0 = fmaxf(mv0, __shfl_xor(mv0, mask, 32));
        mv1 = fmaxf(mv1, __shfl_xor(mv1, mask, 32));
    }
    float Z0 = expf(sv[0] - mv0);
    float Z1 = expf(sv[1] - mv1);
    #pragma unroll
    for (int mask = 1; mask < 32; mask <<= 1) {
        Z0 += __shfl_xor(Z0, mask, 32);
        Z1 += __shfl_xor(Z1, mask, 32);
    }
    float cwA0 = 1.f / Z0;
    float cwA1 = 1.f / Z1;

    // ---- cross-half exchange; evaluate combine in exact reference order ----
    float cwB0 = __shfl_xor(cwA0, 32, 64);
    float cwB1 = __shfl_xor(cwA1, 32, 64);
    float tB0  = __shfl_xor(tv[0], 32, 64);
    float tB1  = __shfl_xor(tv[1], 32, 64);

    float cwv[NV], tvv[NV];
    if (hi == 0) {
        cwv[0] = cwA0; tvv[0] = tv[0];
        cwv[1] = cwA1; tvv[1] = tv[1];
        cwv[2] = cwB0; tvv[2] = tB0;
        cwv[3] = cwB1; tvv[3] = tB1;
    } else {
        cwv[0] = cwB0; tvv[0] = tB0;
        cwv[1] = cwB1; tvv[1] = tB1;
        cwv[2] = cwA0; tvv[2] = tv[0];
        cwv[3] = cwA1; tvv[3] = tv[1];
    }
    float logacc = 0.f;
    float cwsum  = 1e-8f;
    #pragma unroll
    for (int v = 0; v < NV; ++v) {
        logacc += cwv[v]*tvv[v];
        cwsum  += cwv[v];
    }

    float logit = logacc / (cwsum + 1e-7f);
    float m2 = logit;
    #pragma unroll
    for (int mask = 1; mask < 32; mask <<= 1)
        m2 = fmaxf(m2, __shfl_xor(m2, mask, 32));
    float e2 = expf(logit - m2);
    float Z2 = e2;
    #pragma unroll
    for (int mask = 1; mask < 32; mask <<= 1)
        Z2 += __shfl_xor(Z2, mask, 32);
    float aw = e2 / Z2;

    float bv2 = aw; int bi = d;
    #pragma unroll
    for (int mask = 1; mask < 32; mask <<= 1) {
        float ov = __shfl_xor(bv2, mask, 32);
        int   oi = __shfl_xor(bi, mask, 32);
        if (ov > bv2 || (ov == bv2 && oi < bi)) { bv2 = ov; bi = oi; }
    }
    float dsel = __shfl(depth, bi, 32);

    if (hi == 0) {
        out[NPIX + ((b*ND + d)*NH + h)*NW + w] = aw;
        if (d == 0) out[p] = dsel;
    }
}

// ---------------------------------------------------------------------------
// Fallback whole-kernel (original layout) if ws too small
// ---------------------------------------------------------------------------
__global__ __launch_bounds__(256) void mvs_kernel(
    const float* __restrict__ ref_feats,
    const float* __restrict__ src_feats,
    const float* __restrict__ depth_hypo,
    const float* __restrict__ w_reg,
    const float* __restrict__ pw,
    float* __restrict__ out)
{
    int tid = blockIdx.x * 256 + threadIdx.x;
    int d = threadIdx.x & 31;
    int p = tid >> 5;
    if (p >= NPIX) return;
    int w = p % NW;
    int h = (p / NW) % NH;
    int b = p / (NW*NH);
    float xf = (float)w, yf = (float)h;
    float depth = depth_hypo[((b*ND + d)*NH + h)*NW + w];
    float wr[NG];
    #pragma unroll
    for (int g = 0; g < NG; ++g) wr[g] = w_reg[g];
    float logacc = 0.f;
    float cwsum  = 1e-8f;
    for (int v = 0; v < NV; ++v) {
        const float* RT = pw + (b*NV + v)*12;
        double dd  = (double)depth;
        double px_ = ((double)RT[0]*(double)xf + (double)RT[1]*(double)yf + (double)RT[2])*dd + (double)RT[9];
        double py_ = ((double)RT[3]*(double)xf + (double)RT[4]*(double)yf + (double)RT[5])*dd + (double)RT[10];
        double pz_ = ((double)RT[6]*(double)xf + (double)RT[7]*(double)yf + (double)RT[8])*dd + (double)RT[11];
        if (pz_ == 0.0) pz_ = 1e-9;
        double iz = 1.0/pz_;
        double pxd = px_*iz, pyd = py_*iz;
        double x0d = floor(pxd), y0d = floor(pyd);
        int x0i = (int)x0d, y0i = (int)y0d;
        int x1i = x0i + 1,  y1i = y0i + 1;
        float wx = (float)(pxd - x0d), wy = (float)(pyd - y0d);
        float vx0 = (x0i >= 0 && x0i < NW) ? 1.f : 0.f;
        float vx1 = (x1i >= 0 && x1i < NW) ? 1.f : 0.f;
        float vy0 = (y0i >= 0 && y0i < NH) ? 1.f : 0.f;
        float vy1 = (y1i >= 0 && y1i < NH) ? 1.f : 0.f;
        float w00 = (1.f-wx)*(1.f-wy) * vx0*vy0;
        float w01 = wx*(1.f-wy)       * vx1*vy0;
        float w10 = (1.f-wx)*wy       * vx0*vy1;
        float w11 = wx*wy             * vx1*vy1;
        int xc0 = min(max(x0i,0),NW-1), xc1 = min(max(x1i,0),NW-1);
        int yc0 = min(max(y0i,0),NH-1), yc1 = min(max(y1i,0),NH-1);
        int i00 = yc0*NW+xc0, i01 = yc0*NW+xc1;
        int i10 = yc1*NW+xc0, i11 = yc1*NW+xc1;
        const float* sb = src_feats + ((v*NB + b)*NC)*HW;
        const float* rb = ref_feats + ((v*NB + b)*NC)*HW + h*NW + w;
        float acc[NG];
        #pragma unroll
        for (int g = 0; g < NG; ++g) acc[g] = 0.f;
        #pragma unroll
        for (int c = 0; c < NC; ++c) {
            const float* scp = sb + c*HW;
            float f = w00*scp[i00] + w01*scp[i01] + w10*scp[i10] + w11*scp[i11];
            acc[c>>2] += f * rb[c*HW];
        }
        float s = 0.f, t = 0.f;
        #pragma unroll
        for (int g = 0; g < NG; ++g) {
            float cf = 0.25f*acc[g];
            s += cf;
            t += cf*wr[g];
        }
        float m = s;
        #pragma unroll
        for (int mask = 1; mask < 32; mask <<= 1)
            m = fmaxf(m, __shfl_xor(m, mask, 32));
        float e = expf(s - m);
        float Z = e;
        #pragma unroll
        for (int mask = 1; mask < 32; mask <<= 1)
            Z += __shfl_xor(Z, mask, 32);
        float cw = 1.f / Z;
        logacc += cw * t;
        cwsum  += cw;
    }
    float logit = logacc / (cwsum + 1e-7f);
    float m2 = logit;
    #pragma unroll
    for (int mask = 1; mask < 32; mask <<= 1)
        m2 = fmaxf(m2, __shfl_xor(m2, mask, 32));
    float e2 = expf(logit - m2);
    float Z2 = e2;
    #pragma unroll
    for (int mask = 1; mask < 32; mask <<= 1)
        Z2 += __shfl_xor(Z2, mask, 32);
    float aw = e2 / Z2;
    out[NPIX + ((b*ND + d)*NH + h)*NW + w] = aw;
    float bv = aw; int bi = d;
    #pragma unroll
    for (int mask = 1; mask < 32; mask <<= 1) {
        float ov = __shfl_xor(bv, mask, 32);
        int   oi = __shfl_xor(bi, mask, 32);
        if (ov > bv || (ov == bv && oi < bi)) { bv = ov; bi = oi; }
    }
    float dsel = __shfl(depth, bi, 32);
    if (d == 0) out[p] = dsel;
}

extern "C" void kernel_launch(void* const* d_in, const int* in_sizes, int n_in,
                              void* d_out, int out_size, void* d_ws, size_t ws_size,
                              hipStream_t stream) {
    const float* ref_feats  = (const float*)d_in[0];
    const float* src_feats  = (const float*)d_in[1];
    const float* proj       = (const float*)d_in[2];
    const float* depth_hypo = (const float*)d_in[3];
    const float* w_reg      = (const float*)d_in[4];
    float* out = (float*)d_out;

    size_t need = (size_t)2*FEATSZ*sizeof(float) + 96*sizeof(float);
    if (ws_size >= need) {
        float* srcT = (float*)d_ws;
        float* refT = srcT + FEATSZ;
        float* pw   = refT + FEATSZ;
        hipLaunchKernelGGL(proj_setup_kernel, dim3(1), dim3(64), 0, stream, proj, pw);
        dim3 tg(HW/64, NV*NB);
        hipLaunchKernelGGL(transpose_kernel, tg, dim3(256), 0, stream, src_feats, srcT);
        hipLaunchKernelGGL(transpose_kernel, tg, dim3(256), 0, stream, ref_feats, refT);
        hipLaunchKernelGGL(mvs_kernel_t, dim3((NPIX*64)/256), dim3(256), 0, stream,
                           refT, srcT, depth_hypo, w_reg, pw, out);
    } else {
        float* pw = (float*)d_ws;
        hipLaunchKernelGGL(proj_setup_kernel, dim3(1), dim3(64), 0, stream, proj, pw);
        hipLaunchKernelGGL(mvs_kernel, dim3((NPIX*ND)/256), dim3(256), 0, stream,
                           ref_feats, src_feats, depth_hypo, w_reg, pw, out);
    }
}

// Round 7
// 165.275 us; speedup vs baseline: 1.0679x; 1.0679x over previous
//
#include <hip/hip_runtime.h>
#include <math.h>

#define NV 4
#define NB 2
#define NC 32
#define ND 32
#define NH 128
#define NW 160
#define NG 8
#define HW (NH*NW)
#define NPIX (NB*NH*NW)
#define FEATSZ (NV*NB*HW*NC)
#define QMAX 80   // max window slots per half-wave (LDS: 8 halves * 80 q * 8 f * 4B = 20480 B)

// ---------------------------------------------------------------------------
// proj setup (unchanged)
// ---------------------------------------------------------------------------
__global__ void proj_setup_kernel(const float* __restrict__ proj,
                                  float* __restrict__ pw) {
    int t = blockIdx.x * blockDim.x + threadIdx.x;
    if (t >= NB * NV) return;
    int b = t / NV, v = t % NV;
    const float* Eref = proj + ((b*(NV+1) + 0)*2 + 0)*16;
    const float* Kref = proj + ((b*(NV+1) + 0)*2 + 1)*16;
    const float* Esrc = proj + ((b*(NV+1) + (v+1))*2 + 0)*16;
    const float* Ksrc = proj + ((b*(NV+1) + (v+1))*2 + 1)*16;
    float Mr[12], Ms[12];
    for (int i = 0; i < 3; ++i)
        for (int j = 0; j < 4; ++j) {
            float sr = 0.f, ss = 0.f;
            for (int k = 0; k < 3; ++k) {
                sr += Kref[i*4+k] * Eref[k*4+j];
                ss += Ksrc[i*4+k] * Esrc[k*4+j];
            }
            Mr[i*4+j] = sr; Ms[i*4+j] = ss;
        }
    double A[9], a[3];
    for (int i = 0; i < 3; ++i) {
        for (int j = 0; j < 3; ++j) A[i*3+j] = (double)Mr[i*4+j];
        a[i] = (double)Mr[i*4+3];
    }
    double c00 = A[4]*A[8]-A[5]*A[7];
    double c01 = A[5]*A[6]-A[3]*A[8];
    double c02 = A[3]*A[7]-A[4]*A[6];
    double det = A[0]*c00 + A[1]*c01 + A[2]*c02;
    double id  = 1.0/det;
    double Ai[9];
    Ai[0]=c00*id;                 Ai[1]=(A[2]*A[7]-A[1]*A[8])*id; Ai[2]=(A[1]*A[5]-A[2]*A[4])*id;
    Ai[3]=c01*id;                 Ai[4]=(A[0]*A[8]-A[2]*A[6])*id; Ai[5]=(A[2]*A[3]-A[0]*A[5])*id;
    Ai[6]=c02*id;                 Ai[7]=(A[1]*A[6]-A[0]*A[7])*id; Ai[8]=(A[0]*A[4]-A[1]*A[3])*id;
    double R[9], T[3];
    for (int i = 0; i < 3; ++i)
        for (int j = 0; j < 3; ++j) {
            double s = 0.0;
            for (int k = 0; k < 3; ++k) s += (double)Ms[i*4+k] * Ai[k*3+j];
            R[i*3+j] = s;
        }
    for (int i = 0; i < 3; ++i) {
        double s = (double)Ms[i*4+3];
        for (int k = 0; k < 3; ++k) s -= R[i*3+k]*a[k];
        T[i] = s;
    }
    float* o = pw + (b*NV + v)*12;
    for (int i = 0; i < 9; ++i) o[i]   = (float)R[i];
    for (int i = 0; i < 3; ++i) o[9+i] = (float)T[i];
}

// ---------------------------------------------------------------------------
// LDS-tiled transpose: [vb][c][hw] -> [vb][hw][c] (unchanged)
// ---------------------------------------------------------------------------
__global__ __launch_bounds__(256) void transpose_kernel(
    const float* __restrict__ in, float* __restrict__ out) {
    __shared__ float lds[NC][65];
    int vb = blockIdx.y;
    int hwbase = blockIdx.x * 64;
    int t = threadIdx.x;
    #pragma unroll
    for (int r = 0; r < 8; ++r) {
        int c  = (t >> 6) + r*4;
        int hw = t & 63;
        lds[c][hw] = in[(vb*NC + c)*HW + hwbase + hw];
    }
    __syncthreads();
    #pragma unroll
    for (int r = 0; r < 8; ++r) {
        int c  = t & 31;
        int hw = (t >> 5) + r*8;
        out[((size_t)vb*HW + hwbase + hw)*NC + c] = lds[c][hw];
    }
}

// ---------------------------------------------------------------------------
// Main: wave = pixel; half hi owns views {2hi,2hi+1}. Per (pixel,view):
//  1) f64 geometry -> taps + weights
//  2) half-wide bbox of clamped taps (5 shfl steps)
//  3) dot-before-interp: stage D_j(q) = <F_j4(q), R_j4> for the window into
//     the half's PRIVATE LDS slice (coalesced 512B loads; j = lane&7; one
//     ds_write_b32 per load; no barriers - wave-internal ordering)
//  4) per depth-lane: 4 taps x 2 ds_read_b128 -> cf_j = 0.25*sum(w*D_j)
//  5) per-view softmax over depths, cross-half combine (exact ref order)
// Fallback (window > QMAX): R6 direct-gather path, same FP as before.
// ---------------------------------------------------------------------------
__global__ __launch_bounds__(256) void mvs_kernel_t(
    const float* __restrict__ refT,
    const float* __restrict__ srcT,
    const float* __restrict__ depth_hypo,
    const float* __restrict__ w_reg,
    const float* __restrict__ pw,
    float* __restrict__ out)
{
    __shared__ float Dlds[8][QMAX*8];

    int tid = blockIdx.x * 256 + threadIdx.x;
    int lane = threadIdx.x & 63;
    int d  = lane & 31;
    int hi = lane >> 5;            // 0: views 0,1   1: views 2,3
    int p  = tid >> 6;
    if (p >= NPIX) return;
    float* Dh = &Dlds[threadIdx.x >> 5][0];   // per-half private slice
    int sub = lane & 31;
    int jme = sub & 7;

    int w = p % NW;
    int h = (p / NW) % NH;
    int b = p / (NW*NH);
    float xf = (float)w, yf = (float)h;
    float depth = depth_hypo[((b*ND + d)*NH + h)*NW + w];

    float wr[NG];
    #pragma unroll
    for (int g = 0; g < NG; ++g) wr[g] = w_reg[g];

    float sv[2], tv[2];

    #pragma unroll
    for (int vv = 0; vv < 2; ++vv) {
        int v = hi*2 + vv;
        const float* RT = pw + (b*NV + v)*12;
        double dd  = (double)depth;
        double px_ = ((double)RT[0]*(double)xf + (double)RT[1]*(double)yf + (double)RT[2])*dd + (double)RT[9];
        double py_ = ((double)RT[3]*(double)xf + (double)RT[4]*(double)yf + (double)RT[5])*dd + (double)RT[10];
        double pz_ = ((double)RT[6]*(double)xf + (double)RT[7]*(double)yf + (double)RT[8])*dd + (double)RT[11];
        if (pz_ == 0.0) pz_ = 1e-9;
        double iz  = 1.0 / pz_;
        double pxd = px_*iz, pyd = py_*iz;
        double x0d = floor(pxd), y0d = floor(pyd);
        int x0i = (int)x0d, y0i = (int)y0d;
        int x1i = x0i + 1,  y1i = y0i + 1;
        float wx = (float)(pxd - x0d), wy = (float)(pyd - y0d);

        float vx0 = (x0i >= 0 && x0i < NW) ? 1.f : 0.f;
        float vx1 = (x1i >= 0 && x1i < NW) ? 1.f : 0.f;
        float vy0 = (y0i >= 0 && y0i < NH) ? 1.f : 0.f;
        float vy1 = (y1i >= 0 && y1i < NH) ? 1.f : 0.f;
        float w00 = (1.f-wx)*(1.f-wy) * vx0*vy0;
        float w01 = wx*(1.f-wy)       * vx1*vy0;
        float w10 = (1.f-wx)*wy       * vx0*vy1;
        float w11 = wx*wy             * vx1*vy1;
        int xc0 = min(max(x0i,0),NW-1), xc1 = min(max(x1i,0),NW-1);
        int yc0 = min(max(y0i,0),NH-1), yc1 = min(max(y1i,0),NH-1);
        int vb = v*NB + b;

        // half-wide bbox of clamped taps
        int mnx = xc0, mxx = xc1, mny = yc0, mxy = yc1;
        #pragma unroll
        for (int mask = 1; mask < 32; mask <<= 1) {
            mnx = min(mnx, __shfl_xor(mnx, mask, 32));
            mxx = max(mxx, __shfl_xor(mxx, mask, 32));
            mny = min(mny, __shfl_xor(mny, mask, 32));
            mxy = max(mxy, __shfl_xor(mxy, mask, 32));
        }
        int bw = mxx - mnx + 1;
        int bh = mxy - mny + 1;
        int U  = bw * bh;

        const float4* rr = (const float4*)(refT + ((size_t)vb*HW + h*NW + w)*NC);
        float s = 0.f, t = 0.f;

        if (U <= QMAX) {
            // ---- stage D into the half's LDS slice ----
            float4 rfj = rr[jme];          // my ref chunk (j fixed per lane)
            int bw8 = bw * 8;
            for (int yy = 0; yy < bh; ++yy) {
                const float* rowbase = srcT + ((size_t)vb*HW + (size_t)(mny+yy)*NW + mnx)*NC;
                for (int n = sub; n < bw8; n += 32) {
                    // n = xx*8 + j with j == jme; float offset = 4n (contiguous)
                    float4 f = *(const float4*)(rowbase + 4*n);
                    float dv = f.x*rfj.x;
                    dv = fmaf(f.y, rfj.y, dv);
                    dv = fmaf(f.z, rfj.z, dv);
                    dv = fmaf(f.w, rfj.w, dv);
                    Dh[yy*bw8 + n] = dv;
                }
            }
            __builtin_amdgcn_wave_barrier();   // keep stage before tap reads

            int b00 = ((yc0 - mny)*bw + (xc0 - mnx))*8;
            int b01 = ((yc0 - mny)*bw + (xc1 - mnx))*8;
            int b10 = ((yc1 - mny)*bw + (xc0 - mnx))*8;
            int b11 = ((yc1 - mny)*bw + (xc1 - mnx))*8;
            float4 Da00 = *(const float4*)&Dh[b00];
            float4 Db00 = *(const float4*)&Dh[b00+4];
            float4 Da01 = *(const float4*)&Dh[b01];
            float4 Db01 = *(const float4*)&Dh[b01+4];
            float4 Da10 = *(const float4*)&Dh[b10];
            float4 Db10 = *(const float4*)&Dh[b10+4];
            float4 Da11 = *(const float4*)&Dh[b11];
            float4 Db11 = *(const float4*)&Dh[b11+4];

            float cf;
            cf = 0.25f*(w00*Da00.x + w01*Da01.x + w10*Da10.x + w11*Da11.x); s += cf; t += cf*wr[0];
            cf = 0.25f*(w00*Da00.y + w01*Da01.y + w10*Da10.y + w11*Da11.y); s += cf; t += cf*wr[1];
            cf = 0.25f*(w00*Da00.z + w01*Da01.z + w10*Da10.z + w11*Da11.z); s += cf; t += cf*wr[2];
            cf = 0.25f*(w00*Da00.w + w01*Da01.w + w10*Da10.w + w11*Da11.w); s += cf; t += cf*wr[3];
            cf = 0.25f*(w00*Db00.x + w01*Db01.x + w10*Db10.x + w11*Db11.x); s += cf; t += cf*wr[4];
            cf = 0.25f*(w00*Db00.y + w01*Db01.y + w10*Db10.y + w11*Db11.y); s += cf; t += cf*wr[5];
            cf = 0.25f*(w00*Db00.z + w01*Db01.z + w10*Db10.z + w11*Db11.z); s += cf; t += cf*wr[6];
            cf = 0.25f*(w00*Db00.w + w01*Db01.w + w10*Db10.w + w11*Db11.w); s += cf; t += cf*wr[7];
        } else {
            // ---- fallback: direct global gathers (R6 path, exact FP) ----
            int i00 = yc0*NW+xc0, i01 = yc0*NW+xc1;
            int i10 = yc1*NW+xc0, i11 = yc1*NW+xc1;
            const float4* s00 = (const float4*)(srcT + ((size_t)vb*HW + i00)*NC);
            const float4* s01 = (const float4*)(srcT + ((size_t)vb*HW + i01)*NC);
            const float4* s10 = (const float4*)(srcT + ((size_t)vb*HW + i10)*NC);
            const float4* s11 = (const float4*)(srcT + ((size_t)vb*HW + i11)*NC);
            #pragma unroll
            for (int j = 0; j < NG; ++j) {
                float4 a00 = s00[j], a01 = s01[j], a10 = s10[j], a11 = s11[j];
                float4 rf  = rr[j];
                float acc = 0.f;
                float f0 = w00*a00.x + w01*a01.x + w10*a10.x + w11*a11.x;
                acc += f0*rf.x;
                float f1 = w00*a00.y + w01*a01.y + w10*a10.y + w11*a11.y;
                acc += f1*rf.y;
                float f2 = w00*a00.z + w01*a01.z + w10*a10.z + w11*a11.z;
                acc += f2*rf.z;
                float f3 = w00*a00.w + w01*a01.w + w10*a10.w + w11*a11.w;
                acc += f3*rf.w;
                float cf = 0.25f*acc;
                s += cf;
                t += cf*wr[j];
            }
        }
        sv[vv] = s; tv[vv] = t;
    }

    // ---- per-view softmax over depths within the half (2-way ILP) ----
    float mv0 = sv[0], mv1 = sv[1];
    #pragma unroll
    for (int mask = 1; mask < 32; mask <<= 1) {
        mv0 = fmaxf(mv0, __shfl_xor(mv0, mask, 32));
        mv1 = fmaxf(mv1, __shfl_xor(mv1, mask, 32));
    }
    float Z0 = expf(sv[0] - mv0);
    float Z1 = expf(sv[1] - mv1);
    #pragma unroll
    for (int mask = 1; mask < 32; mask <<= 1) {
        Z0 += __shfl_xor(Z0, mask, 32);
        Z1 += __shfl_xor(Z1, mask, 32);
    }
    float cwA0 = 1.f / Z0;
    float cwA1 = 1.f / Z1;

    // ---- cross-half exchange; combine in exact reference order ----
    float cwB0 = __shfl_xor(cwA0, 32, 64);
    float cwB1 = __shfl_xor(cwA1, 32, 64);
    float tB0  = __shfl_xor(tv[0], 32, 64);
    float tB1  = __shfl_xor(tv[1], 32, 64);

    float cwv[NV], tvv[NV];
    if (hi == 0) {
        cwv[0] = cwA0; tvv[0] = tv[0];
        cwv[1] = cwA1; tvv[1] = tv[1];
        cwv[2] = cwB0; tvv[2] = tB0;
        cwv[3] = cwB1; tvv[3] = tB1;
    } else {
        cwv[0] = cwB0; tvv[0] = tB0;
        cwv[1] = cwB1; tvv[1] = tB1;
        cwv[2] = cwA0; tvv[2] = tv[0];
        cwv[3] = cwA1; tvv[3] = tv[1];
    }
    float logacc = 0.f;
    float cwsum  = 1e-8f;
    #pragma unroll
    for (int v = 0; v < NV; ++v) {
        logacc += cwv[v]*tvv[v];
        cwsum  += cwv[v];
    }

    float logit = logacc / (cwsum + 1e-7f);
    float m2 = logit;
    #pragma unroll
    for (int mask = 1; mask < 32; mask <<= 1)
        m2 = fmaxf(m2, __shfl_xor(m2, mask, 32));
    float e2 = expf(logit - m2);
    float Z2 = e2;
    #pragma unroll
    for (int mask = 1; mask < 32; mask <<= 1)
        Z2 += __shfl_xor(Z2, mask, 32);
    float aw = e2 / Z2;

    float bv2 = aw; int bi = d;
    #pragma unroll
    for (int mask = 1; mask < 32; mask <<= 1) {
        float ov = __shfl_xor(bv2, mask, 32);
        int   oi = __shfl_xor(bi, mask, 32);
        if (ov > bv2 || (ov == bv2 && oi < bi)) { bv2 = ov; bi = oi; }
    }
    float dsel = __shfl(depth, bi, 32);

    if (hi == 0) {
        out[NPIX + ((b*ND + d)*NH + h)*NW + w] = aw;
        if (d == 0) out[p] = dsel;
    }
}

// ---------------------------------------------------------------------------
// Fallback whole-kernel (original layout) if ws too small
// ---------------------------------------------------------------------------
__global__ __launch_bounds__(256) void mvs_kernel(
    const float* __restrict__ ref_feats,
    const float* __restrict__ src_feats,
    const float* __restrict__ depth_hypo,
    const float* __restrict__ w_reg,
    const float* __restrict__ pw,
    float* __restrict__ out)
{
    int tid = blockIdx.x * 256 + threadIdx.x;
    int d = threadIdx.x & 31;
    int p = tid >> 5;
    if (p >= NPIX) return;
    int w = p % NW;
    int h = (p / NW) % NH;
    int b = p / (NW*NH);
    float xf = (float)w, yf = (float)h;
    float depth = depth_hypo[((b*ND + d)*NH + h)*NW + w];
    float wr[NG];
    #pragma unroll
    for (int g = 0; g < NG; ++g) wr[g] = w_reg[g];
    float logacc = 0.f;
    float cwsum  = 1e-8f;
    for (int v = 0; v < NV; ++v) {
        const float* RT = pw + (b*NV + v)*12;
        double dd  = (double)depth;
        double px_ = ((double)RT[0]*(double)xf + (double)RT[1]*(double)yf + (double)RT[2])*dd + (double)RT[9];
        double py_ = ((double)RT[3]*(double)xf + (double)RT[4]*(double)yf + (double)RT[5])*dd + (double)RT[10];
        double pz_ = ((double)RT[6]*(double)xf + (double)RT[7]*(double)yf + (double)RT[8])*dd + (double)RT[11];
        if (pz_ == 0.0) pz_ = 1e-9;
        double iz = 1.0/pz_;
        double pxd = px_*iz, pyd = py_*iz;
        double x0d = floor(pxd), y0d = floor(pyd);
        int x0i = (int)x0d, y0i = (int)y0d;
        int x1i = x0i + 1,  y1i = y0i + 1;
        float wx = (float)(pxd - x0d), wy = (float)(pyd - y0d);
        float vx0 = (x0i >= 0 && x0i < NW) ? 1.f : 0.f;
        float vx1 = (x1i >= 0 && x1i < NW) ? 1.f : 0.f;
        float vy0 = (y0i >= 0 && y0i < NH) ? 1.f : 0.f;
        float vy1 = (y1i >= 0 && y1i < NH) ? 1.f : 0.f;
        float w00 = (1.f-wx)*(1.f-wy) * vx0*vy0;
        float w01 = wx*(1.f-wy)       * vx1*vy0;
        float w10 = (1.f-wx)*wy       * vx0*vy1;
        float w11 = wx*wy             * vx1*vy1;
        int xc0 = min(max(x0i,0),NW-1), xc1 = min(max(x1i,0),NW-1);
        int yc0 = min(max(y0i,0),NH-1), yc1 = min(max(y1i,0),NH-1);
        int i00 = yc0*NW+xc0, i01 = yc0*NW+xc1;
        int i10 = yc1*NW+xc0, i11 = yc1*NW+xc1;
        const float* sb = src_feats + ((v*NB + b)*NC)*HW;
        const float* rb = ref_feats + ((v*NB + b)*NC)*HW + h*NW + w;
        float acc[NG];
        #pragma unroll
        for (int g = 0; g < NG; ++g) acc[g] = 0.f;
        #pragma unroll
        for (int c = 0; c < NC; ++c) {
            const float* scp = sb + c*HW;
            float f = w00*scp[i00] + w01*scp[i01] + w10*scp[i10] + w11*scp[i11];
            acc[c>>2] += f * rb[c*HW];
        }
        float s = 0.f, t = 0.f;
        #pragma unroll
        for (int g = 0; g < NG; ++g) {
            float cf = 0.25f*acc[g];
            s += cf;
            t += cf*wr[g];
        }
        float m = s;
        #pragma unroll
        for (int mask = 1; mask < 32; mask <<= 1)
            m = fmaxf(m, __shfl_xor(m, mask, 32));
        float e = expf(s - m);
        float Z = e;
        #pragma unroll
        for (int mask = 1; mask < 32; mask <<= 1)
            Z += __shfl_xor(Z, mask, 32);
        float cw = 1.f / Z;
        logacc += cw * t;
        cwsum  += cw;
    }
    float logit = logacc / (cwsum + 1e-7f);
    float m2 = logit;
    #pragma unroll
    for (int mask = 1; mask < 32; mask <<= 1)
        m2 = fmaxf(m2, __shfl_xor(m2, mask, 32));
    float e2 = expf(logit - m2);
    float Z2 = e2;
    #pragma unroll
    for (int mask = 1; mask < 32; mask <<= 1)
        Z2 += __shfl_xor(Z2, mask, 32);
    float aw = e2 / Z2;
    out[NPIX + ((b*ND + d)*NH + h)*NW + w] = aw;
    float bv = aw; int bi = d;
    #pragma unroll
    for (int mask = 1; mask < 32; mask <<= 1) {
        float ov = __shfl_xor(bv, mask, 32);
        int   oi = __shfl_xor(bi, mask, 32);
        if (ov > bv || (ov == bv && oi < bi)) { bv = ov; bi = oi; }
    }
    float dsel = __shfl(depth, bi, 32);
    if (d == 0) out[p] = dsel;
}

extern "C" void kernel_launch(void* const* d_in, const int* in_sizes, int n_in,
                              void* d_out, int out_size, void* d_ws, size_t ws_size,
                              hipStream_t stream) {
    const float* ref_feats  = (const float*)d_in[0];
    const float* src_feats  = (const float*)d_in[1];
    const float* proj       = (const float*)d_in[2];
    const float* depth_hypo = (const float*)d_in[3];
    const float* w_reg      = (const float*)d_in[4];
    float* out = (float*)d_out;

    size_t need = (size_t)2*FEATSZ*sizeof(float) + 96*sizeof(float);
    if (ws_size >= need) {
        float* srcT = (float*)d_ws;
        float* refT = srcT + FEATSZ;
        float* pw   = refT + FEATSZ;
        hipLaunchKernelGGL(proj_setup_kernel, dim3(1), dim3(64), 0, stream, proj, pw);
        dim3 tg(HW/64, NV*NB);
        hipLaunchKernelGGL(transpose_kernel, tg, dim3(256), 0, stream, src_feats, srcT);
        hipLaunchKernelGGL(transpose_kernel, tg, dim3(256), 0, stream, ref_feats, refT);
        hipLaunchKernelGGL(mvs_kernel_t, dim3((NPIX*64)/256), dim3(256), 0, stream,
                           refT, srcT, depth_hypo, w_reg, pw, out);
    } else {
        float* pw = (float*)d_ws;
        hipLaunchKernelGGL(proj_setup_kernel, dim3(1), dim3(64), 0, stream, proj, pw);
        hipLaunchKernelGGL(mvs_kernel, dim3((NPIX*ND)/256), dim3(256), 0, stream,
                           ref_feats, src_feats, depth_hypo, w_reg, pw, out);
    }
}

// Round 8
// 157.117 us; speedup vs baseline: 1.1233x; 1.0519x over previous
//
#include <hip/hip_runtime.h>
#include <math.h>

#define NV 4
#define NB 2
#define NC 32
#define ND 32
#define NH 128
#define NW 160
#define NG 8
#define HW (NH*NW)
#define NPIX (NB*NH*NW)
#define FEATSZ (NV*NB*HW*NC)
#define QMAX 80   // max window slots per half-wave

// ---------------------------------------------------------------------------
// proj setup (unchanged)
// ---------------------------------------------------------------------------
__global__ void proj_setup_kernel(const float* __restrict__ proj,
                                  float* __restrict__ pw) {
    int t = blockIdx.x * blockDim.x + threadIdx.x;
    if (t >= NB * NV) return;
    int b = t / NV, v = t % NV;
    const float* Eref = proj + ((b*(NV+1) + 0)*2 + 0)*16;
    const float* Kref = proj + ((b*(NV+1) + 0)*2 + 1)*16;
    const float* Esrc = proj + ((b*(NV+1) + (v+1))*2 + 0)*16;
    const float* Ksrc = proj + ((b*(NV+1) + (v+1))*2 + 1)*16;
    float Mr[12], Ms[12];
    for (int i = 0; i < 3; ++i)
        for (int j = 0; j < 4; ++j) {
            float sr = 0.f, ss = 0.f;
            for (int k = 0; k < 3; ++k) {
                sr += Kref[i*4+k] * Eref[k*4+j];
                ss += Ksrc[i*4+k] * Esrc[k*4+j];
            }
            Mr[i*4+j] = sr; Ms[i*4+j] = ss;
        }
    double A[9], a[3];
    for (int i = 0; i < 3; ++i) {
        for (int j = 0; j < 3; ++j) A[i*3+j] = (double)Mr[i*4+j];
        a[i] = (double)Mr[i*4+3];
    }
    double c00 = A[4]*A[8]-A[5]*A[7];
    double c01 = A[5]*A[6]-A[3]*A[8];
    double c02 = A[3]*A[7]-A[4]*A[6];
    double det = A[0]*c00 + A[1]*c01 + A[2]*c02;
    double id  = 1.0/det;
    double Ai[9];
    Ai[0]=c00*id;                 Ai[1]=(A[2]*A[7]-A[1]*A[8])*id; Ai[2]=(A[1]*A[5]-A[2]*A[4])*id;
    Ai[3]=c01*id;                 Ai[4]=(A[0]*A[8]-A[2]*A[6])*id; Ai[5]=(A[2]*A[3]-A[0]*A[5])*id;
    Ai[6]=c02*id;                 Ai[7]=(A[1]*A[6]-A[0]*A[7])*id; Ai[8]=(A[0]*A[4]-A[1]*A[3])*id;
    double R[9], T[3];
    for (int i = 0; i < 3; ++i)
        for (int j = 0; j < 3; ++j) {
            double s = 0.0;
            for (int k = 0; k < 3; ++k) s += (double)Ms[i*4+k] * Ai[k*3+j];
            R[i*3+j] = s;
        }
    for (int i = 0; i < 3; ++i) {
        double s = (double)Ms[i*4+3];
        for (int k = 0; k < 3; ++k) s -= R[i*3+k]*a[k];
        T[i] = s;
    }
    float* o = pw + (b*NV + v)*12;
    for (int i = 0; i < 9; ++i) o[i]   = (float)R[i];
    for (int i = 0; i < 3; ++i) o[9+i] = (float)T[i];
}

// ---------------------------------------------------------------------------
// LDS-tiled transpose: [vb][c][hw] -> [vb][hw][c] (unchanged)
// ---------------------------------------------------------------------------
__global__ __launch_bounds__(256) void transpose_kernel(
    const float* __restrict__ in, float* __restrict__ out) {
    __shared__ float lds[NC][65];
    int vb = blockIdx.y;
    int hwbase = blockIdx.x * 64;
    int t = threadIdx.x;
    #pragma unroll
    for (int r = 0; r < 8; ++r) {
        int c  = (t >> 6) + r*4;
        int hw = t & 63;
        lds[c][hw] = in[(vb*NC + c)*HW + hwbase + hw];
    }
    __syncthreads();
    #pragma unroll
    for (int r = 0; r < 8; ++r) {
        int c  = t & 31;
        int hw = (t >> 5) + r*8;
        out[((size_t)vb*HW + hwbase + hw)*NC + c] = lds[c][hw];
    }
}

// ---------------------------------------------------------------------------
// Geometry precompute: half-wave = one (view, pixel), 32 lanes = 32 depths.
// Exact same f64 chain as R7's main kernel -> bit-identical x0,y0,wx,wy.
// Stores packed clamped int16 x0,y0 (clamp to [-2,NW]/[-2,NH] preserves all
// validity tests and index clamps) + exact f32 wx,wy + per-(view,pixel) bbox
// (same 32-lane butterfly as R7 -> bit-identical box).
// ---------------------------------------------------------------------------
__global__ __launch_bounds__(256) void geo_precompute_kernel(
    const float* __restrict__ depth_hypo,
    const float* __restrict__ pw,
    unsigned int* __restrict__ geoXY,
    float2* __restrict__ geoW,
    int4* __restrict__ bboxA)
{
    int tid = blockIdx.x * 256 + threadIdx.x;
    int half = tid >> 5;
    int d    = tid & 31;
    if (half >= NV*NPIX) return;
    int v = half / NPIX;
    int p = half - v*NPIX;
    int w = p % NW;
    int h = (p / NW) % NH;
    int b = p / (NW*NH);
    float xf = (float)w, yf = (float)h;
    float depth = depth_hypo[((b*ND + d)*NH + h)*NW + w];

    const float* RT = pw + (b*NV + v)*12;
    double dd  = (double)depth;
    double px_ = ((double)RT[0]*(double)xf + (double)RT[1]*(double)yf + (double)RT[2])*dd + (double)RT[9];
    double py_ = ((double)RT[3]*(double)xf + (double)RT[4]*(double)yf + (double)RT[5])*dd + (double)RT[10];
    double pz_ = ((double)RT[6]*(double)xf + (double)RT[7]*(double)yf + (double)RT[8])*dd + (double)RT[11];
    if (pz_ == 0.0) pz_ = 1e-9;
    double iz  = 1.0 / pz_;
    double pxd = px_*iz, pyd = py_*iz;
    double x0d = floor(pxd), y0d = floor(pyd);
    int x0i = (int)x0d, y0i = (int)y0d;
    float wx = (float)(pxd - x0d), wy = (float)(pyd - y0d);

    // clamp to int16-safe range; preserves validity + clamp semantics
    int x0s = min(max(x0i, -2), NW);
    int y0s = min(max(y0i, -2), NH);
    geoXY[(size_t)half*ND + d] = ((unsigned int)(unsigned short)(short)x0s)
                               | ((unsigned int)(unsigned short)(short)y0s << 16);
    geoW [(size_t)half*ND + d] = make_float2(wx, wy);

    // bbox of clamped taps over the 32 depths (same butterfly as R7)
    int xc0 = min(max(x0i,0),NW-1), xc1 = min(max(x0i+1,0),NW-1);
    int yc0 = min(max(y0i,0),NH-1), yc1 = min(max(y0i+1,0),NH-1);
    int mnx = xc0, mxx = xc1, mny = yc0, mxy = yc1;
    #pragma unroll
    for (int mask = 1; mask < 32; mask <<= 1) {
        mnx = min(mnx, __shfl_xor(mnx, mask, 32));
        mxx = max(mxx, __shfl_xor(mxx, mask, 32));
        mny = min(mny, __shfl_xor(mny, mask, 32));
        mxy = max(mxy, __shfl_xor(mxy, mask, 32));
    }
    if (d == 0) bboxA[half] = make_int4(mnx, mxx, mny, mxy);
}

// ---------------------------------------------------------------------------
// Main (geometry-free): wave = pixel; half hi owns views {2hi,2hi+1}.
// Per view: load geo (4B+8B coalesced) + bbox (16B uniform), compute weights
// (same f32 ops as R7), stage D into private LDS slice, taps via ds_read_b128,
// softmax/combine identical to R7. All FP bit-identical to R7.
// ---------------------------------------------------------------------------
__global__ __launch_bounds__(256) void mvs_kernel_g(
    const float* __restrict__ refT,
    const float* __restrict__ srcT,
    const float* __restrict__ depth_hypo,
    const float* __restrict__ w_reg,
    const unsigned int* __restrict__ geoXY,
    const float2* __restrict__ geoW,
    const int4* __restrict__ bboxA,
    float* __restrict__ out)
{
    __shared__ float Dlds[8][QMAX*8];

    int tid = blockIdx.x * 256 + threadIdx.x;
    int lane = threadIdx.x & 63;
    int d  = lane & 31;
    int hi = lane >> 5;
    int p  = tid >> 6;
    if (p >= NPIX) return;
    float* Dh = &Dlds[threadIdx.x >> 5][0];
    int sub = lane & 31;
    int jme = sub & 7;

    int w = p % NW;
    int h = (p / NW) % NH;
    int b = p / (NW*NH);
    float depth = depth_hypo[((b*ND + d)*NH + h)*NW + w];

    float wr[NG];
    #pragma unroll
    for (int g = 0; g < NG; ++g) wr[g] = w_reg[g];

    float sv[2], tv[2];

    #pragma unroll
    for (int vv = 0; vv < 2; ++vv) {
        int v = hi*2 + vv;
        size_t half = (size_t)v*NPIX + p;
        unsigned int gxy = geoXY[half*ND + d];
        float2 wxy = geoW[half*ND + d];
        int4 bb = bboxA[half];
        int x0i = (int)(short)(gxy & 0xffffu);
        int y0i = (int)(short)(gxy >> 16);
        int x1i = x0i + 1, y1i = y0i + 1;
        float wx = wxy.x, wy = wxy.y;

        float vx0 = (x0i >= 0 && x0i < NW) ? 1.f : 0.f;
        float vx1 = (x1i >= 0 && x1i < NW) ? 1.f : 0.f;
        float vy0 = (y0i >= 0 && y0i < NH) ? 1.f : 0.f;
        float vy1 = (y1i >= 0 && y1i < NH) ? 1.f : 0.f;
        float w00 = (1.f-wx)*(1.f-wy) * vx0*vy0;
        float w01 = wx*(1.f-wy)       * vx1*vy0;
        float w10 = (1.f-wx)*wy       * vx0*vy1;
        float w11 = wx*wy             * vx1*vy1;
        int xc0 = min(max(x0i,0),NW-1), xc1 = min(max(x1i,0),NW-1);
        int yc0 = min(max(y0i,0),NH-1), yc1 = min(max(y1i,0),NH-1);
        int vb = v*NB + b;

        int mnx = bb.x, mxx = bb.y, mny = bb.z, mxy = bb.w;
        int bw = mxx - mnx + 1;
        int bh = mxy - mny + 1;
        int U  = bw * bh;

        const float4* rr = (const float4*)(refT + ((size_t)vb*HW + h*NW + w)*NC);
        float s = 0.f, t = 0.f;

        if (U <= QMAX) {
            float4 rfj = rr[jme];
            int bw8 = bw * 8;
            for (int yy = 0; yy < bh; ++yy) {
                const float* rowbase = srcT + ((size_t)vb*HW + (size_t)(mny+yy)*NW + mnx)*NC;
                for (int n = sub; n < bw8; n += 32) {
                    float4 f = *(const float4*)(rowbase + 4*n);
                    float dv = f.x*rfj.x;
                    dv = fmaf(f.y, rfj.y, dv);
                    dv = fmaf(f.z, rfj.z, dv);
                    dv = fmaf(f.w, rfj.w, dv);
                    Dh[yy*bw8 + n] = dv;
                }
            }
            __builtin_amdgcn_wave_barrier();

            int b00 = ((yc0 - mny)*bw + (xc0 - mnx))*8;
            int b01 = ((yc0 - mny)*bw + (xc1 - mnx))*8;
            int b10 = ((yc1 - mny)*bw + (xc0 - mnx))*8;
            int b11 = ((yc1 - mny)*bw + (xc1 - mnx))*8;
            float4 Da00 = *(const float4*)&Dh[b00];
            float4 Db00 = *(const float4*)&Dh[b00+4];
            float4 Da01 = *(const float4*)&Dh[b01];
            float4 Db01 = *(const float4*)&Dh[b01+4];
            float4 Da10 = *(const float4*)&Dh[b10];
            float4 Db10 = *(const float4*)&Dh[b10+4];
            float4 Da11 = *(const float4*)&Dh[b11];
            float4 Db11 = *(const float4*)&Dh[b11+4];

            float cf;
            cf = 0.25f*(w00*Da00.x + w01*Da01.x + w10*Da10.x + w11*Da11.x); s += cf; t += cf*wr[0];
            cf = 0.25f*(w00*Da00.y + w01*Da01.y + w10*Da10.y + w11*Da11.y); s += cf; t += cf*wr[1];
            cf = 0.25f*(w00*Da00.z + w01*Da01.z + w10*Da10.z + w11*Da11.z); s += cf; t += cf*wr[2];
            cf = 0.25f*(w00*Da00.w + w01*Da01.w + w10*Da10.w + w11*Da11.w); s += cf; t += cf*wr[3];
            cf = 0.25f*(w00*Db00.x + w01*Db01.x + w10*Db10.x + w11*Db11.x); s += cf; t += cf*wr[4];
            cf = 0.25f*(w00*Db00.y + w01*Db01.y + w10*Db10.y + w11*Db11.y); s += cf; t += cf*wr[5];
            cf = 0.25f*(w00*Db00.z + w01*Db01.z + w10*Db10.z + w11*Db11.z); s += cf; t += cf*wr[6];
            cf = 0.25f*(w00*Db00.w + w01*Db01.w + w10*Db10.w + w11*Db11.w); s += cf; t += cf*wr[7];
        } else {
            int i00 = yc0*NW+xc0, i01 = yc0*NW+xc1;
            int i10 = yc1*NW+xc0, i11 = yc1*NW+xc1;
            const float4* s00 = (const float4*)(srcT + ((size_t)vb*HW + i00)*NC);
            const float4* s01 = (const float4*)(srcT + ((size_t)vb*HW + i01)*NC);
            const float4* s10 = (const float4*)(srcT + ((size_t)vb*HW + i10)*NC);
            const float4* s11 = (const float4*)(srcT + ((size_t)vb*HW + i11)*NC);
            #pragma unroll
            for (int j = 0; j < NG; ++j) {
                float4 a00 = s00[j], a01 = s01[j], a10 = s10[j], a11 = s11[j];
                float4 rf  = rr[j];
                float acc = 0.f;
                float f0 = w00*a00.x + w01*a01.x + w10*a10.x + w11*a11.x;
                acc += f0*rf.x;
                float f1 = w00*a00.y + w01*a01.y + w10*a10.y + w11*a11.y;
                acc += f1*rf.y;
                float f2 = w00*a00.z + w01*a01.z + w10*a10.z + w11*a11.z;
                acc += f2*rf.z;
                float f3 = w00*a00.w + w01*a01.w + w10*a10.w + w11*a11.w;
                acc += f3*rf.w;
                float cf = 0.25f*acc;
                s += cf;
                t += cf*wr[j];
            }
        }
        sv[vv] = s; tv[vv] = t;
    }

    float mv0 = sv[0], mv1 = sv[1];
    #pragma unroll
    for (int mask = 1; mask < 32; mask <<= 1) {
        mv0 = fmaxf(mv0, __shfl_xor(mv0, mask, 32));
        mv1 = fmaxf(mv1, __shfl_xor(mv1, mask, 32));
    }
    float Z0 = expf(sv[0] - mv0);
    float Z1 = expf(sv[1] - mv1);
    #pragma unroll
    for (int mask = 1; mask < 32; mask <<= 1) {
        Z0 += __shfl_xor(Z0, mask, 32);
        Z1 += __shfl_xor(Z1, mask, 32);
    }
    float cwA0 = 1.f / Z0;
    float cwA1 = 1.f / Z1;

    float cwB0 = __shfl_xor(cwA0, 32, 64);
    float cwB1 = __shfl_xor(cwA1, 32, 64);
    float tB0  = __shfl_xor(tv[0], 32, 64);
    float tB1  = __shfl_xor(tv[1], 32, 64);

    float cwv[NV], tvv[NV];
    if (hi == 0) {
        cwv[0] = cwA0; tvv[0] = tv[0];
        cwv[1] = cwA1; tvv[1] = tv[1];
        cwv[2] = cwB0; tvv[2] = tB0;
        cwv[3] = cwB1; tvv[3] = tB1;
    } else {
        cwv[0] = cwB0; tvv[0] = tB0;
        cwv[1] = cwB1; tvv[1] = tB1;
        cwv[2] = cwA0; tvv[2] = tv[0];
        cwv[3] = cwA1; tvv[3] = tv[1];
    }
    float logacc = 0.f;
    float cwsum  = 1e-8f;
    #pragma unroll
    for (int v = 0; v < NV; ++v) {
        logacc += cwv[v]*tvv[v];
        cwsum  += cwv[v];
    }

    float logit = logacc / (cwsum + 1e-7f);
    float m2 = logit;
    #pragma unroll
    for (int mask = 1; mask < 32; mask <<= 1)
        m2 = fmaxf(m2, __shfl_xor(m2, mask, 32));
    float e2 = expf(logit - m2);
    float Z2 = e2;
    #pragma unroll
    for (int mask = 1; mask < 32; mask <<= 1)
        Z2 += __shfl_xor(Z2, mask, 32);
    float aw = e2 / Z2;

    float bv2 = aw; int bi = d;
    #pragma unroll
    for (int mask = 1; mask < 32; mask <<= 1) {
        float ov = __shfl_xor(bv2, mask, 32);
        int   oi = __shfl_xor(bi, mask, 32);
        if (ov > bv2 || (ov == bv2 && oi < bi)) { bv2 = ov; bi = oi; }
    }
    float dsel = __shfl(depth, bi, 32);

    if (hi == 0) {
        out[NPIX + ((b*ND + d)*NH + h)*NW + w] = aw;
        if (d == 0) out[p] = dsel;
    }
}

// ---------------------------------------------------------------------------
// R7 mid path (transposed feats, in-kernel f64 geometry) if ws fits only 2x FEATSZ
// ---------------------------------------------------------------------------
__global__ __launch_bounds__(256) void mvs_kernel_t(
    const float* __restrict__ refT,
    const float* __restrict__ srcT,
    const float* __restrict__ depth_hypo,
    const float* __restrict__ w_reg,
    const float* __restrict__ pw,
    float* __restrict__ out)
{
    __shared__ float Dlds[8][QMAX*8];
    int tid = blockIdx.x * 256 + threadIdx.x;
    int lane = threadIdx.x & 63;
    int d  = lane & 31;
    int hi = lane >> 5;
    int p  = tid >> 6;
    if (p >= NPIX) return;
    float* Dh = &Dlds[threadIdx.x >> 5][0];
    int sub = lane & 31;
    int jme = sub & 7;
    int w = p % NW;
    int h = (p / NW) % NH;
    int b = p / (NW*NH);
    float xf = (float)w, yf = (float)h;
    float depth = depth_hypo[((b*ND + d)*NH + h)*NW + w];
    float wr[NG];
    #pragma unroll
    for (int g = 0; g < NG; ++g) wr[g] = w_reg[g];
    float sv[2], tv[2];
    #pragma unroll
    for (int vv = 0; vv < 2; ++vv) {
        int v = hi*2 + vv;
        const float* RT = pw + (b*NV + v)*12;
        double dd  = (double)depth;
        double px_ = ((double)RT[0]*(double)xf + (double)RT[1]*(double)yf + (double)RT[2])*dd + (double)RT[9];
        double py_ = ((double)RT[3]*(double)xf + (double)RT[4]*(double)yf + (double)RT[5])*dd + (double)RT[10];
        double pz_ = ((double)RT[6]*(double)xf + (double)RT[7]*(double)yf + (double)RT[8])*dd + (double)RT[11];
        if (pz_ == 0.0) pz_ = 1e-9;
        double iz  = 1.0 / pz_;
        double pxd = px_*iz, pyd = py_*iz;
        double x0d = floor(pxd), y0d = floor(pyd);
        int x0i = (int)x0d, y0i = (int)y0d;
        int x1i = x0i + 1,  y1i = y0i + 1;
        float wx = (float)(pxd - x0d), wy = (float)(pyd - y0d);
        float vx0 = (x0i >= 0 && x0i < NW) ? 1.f : 0.f;
        float vx1 = (x1i >= 0 && x1i < NW) ? 1.f : 0.f;
        float vy0 = (y0i >= 0 && y0i < NH) ? 1.f : 0.f;
        float vy1 = (y1i >= 0 && y1i < NH) ? 1.f : 0.f;
        float w00 = (1.f-wx)*(1.f-wy) * vx0*vy0;
        float w01 = wx*(1.f-wy)       * vx1*vy0;
        float w10 = (1.f-wx)*wy       * vx0*vy1;
        float w11 = wx*wy             * vx1*vy1;
        int xc0 = min(max(x0i,0),NW-1), xc1 = min(max(x1i,0),NW-1);
        int yc0 = min(max(y0i,0),NH-1), yc1 = min(max(y1i,0),NH-1);
        int vb = v*NB + b;
        int mnx = xc0, mxx = xc1, mny = yc0, mxy = yc1;
        #pragma unroll
        for (int mask = 1; mask < 32; mask <<= 1) {
            mnx = min(mnx, __shfl_xor(mnx, mask, 32));
            mxx = max(mxx, __shfl_xor(mxx, mask, 32));
            mny = min(mny, __shfl_xor(mny, mask, 32));
            mxy = max(mxy, __shfl_xor(mxy, mask, 32));
        }
        int bw = mxx - mnx + 1;
        int bh = mxy - mny + 1;
        int U  = bw * bh;
        const float4* rr = (const float4*)(refT + ((size_t)vb*HW + h*NW + w)*NC);
        float s = 0.f, t = 0.f;
        if (U <= QMAX) {
            float4 rfj = rr[jme];
            int bw8 = bw * 8;
            for (int yy = 0; yy < bh; ++yy) {
                const float* rowbase = srcT + ((size_t)vb*HW + (size_t)(mny+yy)*NW + mnx)*NC;
                for (int n = sub; n < bw8; n += 32) {
                    float4 f = *(const float4*)(rowbase + 4*n);
                    float dv = f.x*rfj.x;
                    dv = fmaf(f.y, rfj.y, dv);
                    dv = fmaf(f.z, rfj.z, dv);
                    dv = fmaf(f.w, rfj.w, dv);
                    Dh[yy*bw8 + n] = dv;
                }
            }
            __builtin_amdgcn_wave_barrier();
            int b00 = ((yc0 - mny)*bw + (xc0 - mnx))*8;
            int b01 = ((yc0 - mny)*bw + (xc1 - mnx))*8;
            int b10 = ((yc1 - mny)*bw + (xc0 - mnx))*8;
            int b11 = ((yc1 - mny)*bw + (xc1 - mnx))*8;
            float4 Da00 = *(const float4*)&Dh[b00];
            float4 Db00 = *(const float4*)&Dh[b00+4];
            float4 Da01 = *(const float4*)&Dh[b01];
            float4 Db01 = *(const float4*)&Dh[b01+4];
            float4 Da10 = *(const float4*)&Dh[b10];
            float4 Db10 = *(const float4*)&Dh[b10+4];
            float4 Da11 = *(const float4*)&Dh[b11];
            float4 Db11 = *(const float4*)&Dh[b11+4];
            float cf;
            cf = 0.25f*(w00*Da00.x + w01*Da01.x + w10*Da10.x + w11*Da11.x); s += cf; t += cf*wr[0];
            cf = 0.25f*(w00*Da00.y + w01*Da01.y + w10*Da10.y + w11*Da11.y); s += cf; t += cf*wr[1];
            cf = 0.25f*(w00*Da00.z + w01*Da01.z + w10*Da10.z + w11*Da11.z); s += cf; t += cf*wr[2];
            cf = 0.25f*(w00*Da00.w + w01*Da01.w + w10*Da10.w + w11*Da11.w); s += cf; t += cf*wr[3];
            cf = 0.25f*(w00*Db00.x + w01*Db01.x + w10*Db10.x + w11*Db11.x); s += cf; t += cf*wr[4];
            cf = 0.25f*(w00*Db00.y + w01*Db01.y + w10*Db10.y + w11*Db11.y); s += cf; t += cf*wr[5];
            cf = 0.25f*(w00*Db00.z + w01*Db01.z + w10*Db10.z + w11*Db11.z); s += cf; t += cf*wr[6];
            cf = 0.25f*(w00*Db00.w + w01*Db01.w + w10*Db10.w + w11*Db11.w); s += cf; t += cf*wr[7];
        } else {
            int i00 = yc0*NW+xc0, i01 = yc0*NW+xc1;
            int i10 = yc1*NW+xc0, i11 = yc1*NW+xc1;
            const float4* s00 = (const float4*)(srcT + ((size_t)vb*HW + i00)*NC);
            const float4* s01 = (const float4*)(srcT + ((size_t)vb*HW + i01)*NC);
            const float4* s10 = (const float4*)(srcT + ((size_t)vb*HW + i10)*NC);
            const float4* s11 = (const float4*)(srcT + ((size_t)vb*HW + i11)*NC);
            #pragma unroll
            for (int j = 0; j < NG; ++j) {
                float4 a00 = s00[j], a01 = s01[j], a10 = s10[j], a11 = s11[j];
                float4 rf  = rr[j];
                float acc = 0.f;
                float f0 = w00*a00.x + w01*a01.x + w10*a10.x + w11*a11.x;
                acc += f0*rf.x;
                float f1 = w00*a00.y + w01*a01.y + w10*a10.y + w11*a11.y;
                acc += f1*rf.y;
                float f2 = w00*a00.z + w01*a01.z + w10*a10.z + w11*a11.z;
                acc += f2*rf.z;
                float f3 = w00*a00.w + w01*a01.w + w10*a10.w + w11*a11.w;
                acc += f3*rf.w;
                float cf = 0.25f*acc;
                s += cf;
                t += cf*wr[j];
            }
        }
        sv[vv] = s; tv[vv] = t;
    }
    float mv0 = sv[0], mv1 = sv[1];
    #pragma unroll
    for (int mask = 1; mask < 32; mask <<= 1) {
        mv0 = fmaxf(mv0, __shfl_xor(mv0, mask, 32));
        mv1 = fmaxf(mv1, __shfl_xor(mv1, mask, 32));
    }
    float Z0 = expf(sv[0] - mv0);
    float Z1 = expf(sv[1] - mv1);
    #pragma unroll
    for (int mask = 1; mask < 32; mask <<= 1) {
        Z0 += __shfl_xor(Z0, mask, 32);
        Z1 += __shfl_xor(Z1, mask, 32);
    }
    float cwA0 = 1.f / Z0;
    float cwA1 = 1.f / Z1;
    float cwB0 = __shfl_xor(cwA0, 32, 64);
    float cwB1 = __shfl_xor(cwA1, 32, 64);
    float tB0  = __shfl_xor(tv[0], 32, 64);
    float tB1  = __shfl_xor(tv[1], 32, 64);
    float cwv[NV], tvv[NV];
    if (hi == 0) {
        cwv[0] = cwA0; tvv[0] = tv[0];
        cwv[1] = cwA1; tvv[1] = tv[1];
        cwv[2] = cwB0; tvv[2] = tB0;
        cwv[3] = cwB1; tvv[3] = tB1;
    } else {
        cwv[0] = cwB0; tvv[0] = tB0;
        cwv[1] = cwB1; tvv[1] = tB1;
        cwv[2] = cwA0; tvv[2] = tv[0];
        cwv[3] = cwA1; tvv[3] = tv[1];
    }
    float logacc = 0.f;
    float cwsum  = 1e-8f;
    #pragma unroll
    for (int v = 0; v < NV; ++v) {
        logacc += cwv[v]*tvv[v];
        cwsum  += cwv[v];
    }
    float logit = logacc / (cwsum + 1e-7f);
    float m2 = logit;
    #pragma unroll
    for (int mask = 1; mask < 32; mask <<= 1)
        m2 = fmaxf(m2, __shfl_xor(m2, mask, 32));
    float e2 = expf(logit - m2);
    float Z2 = e2;
    #pragma unroll
    for (int mask = 1; mask < 32; mask <<= 1)
        Z2 += __shfl_xor(Z2, mask, 32);
    float aw = e2 / Z2;
    float bv2 = aw; int bi = d;
    #pragma unroll
    for (int mask = 1; mask < 32; mask <<= 1) {
        float ov = __shfl_xor(bv2, mask, 32);
        int   oi = __shfl_xor(bi, mask, 32);
        if (ov > bv2 || (ov == bv2 && oi < bi)) { bv2 = ov; bi = oi; }
    }
    float dsel = __shfl(depth, bi, 32);
    if (hi == 0) {
        out[NPIX + ((b*ND + d)*NH + h)*NW + w] = aw;
        if (d == 0) out[p] = dsel;
    }
}

// ---------------------------------------------------------------------------
// Final fallback (original layout) if ws tiny
// ---------------------------------------------------------------------------
__global__ __launch_bounds__(256) void mvs_kernel(
    const float* __restrict__ ref_feats,
    const float* __restrict__ src_feats,
    const float* __restrict__ depth_hypo,
    const float* __restrict__ w_reg,
    const float* __restrict__ pw,
    float* __restrict__ out)
{
    int tid = blockIdx.x * 256 + threadIdx.x;
    int d = threadIdx.x & 31;
    int p = tid >> 5;
    if (p >= NPIX) return;
    int w = p % NW;
    int h = (p / NW) % NH;
    int b = p / (NW*NH);
    float xf = (float)w, yf = (float)h;
    float depth = depth_hypo[((b*ND + d)*NH + h)*NW + w];
    float wr[NG];
    #pragma unroll
    for (int g = 0; g < NG; ++g) wr[g] = w_reg[g];
    float logacc = 0.f;
    float cwsum  = 1e-8f;
    for (int v = 0; v < NV; ++v) {
        const float* RT = pw + (b*NV + v)*12;
        double dd  = (double)depth;
        double px_ = ((double)RT[0]*(double)xf + (double)RT[1]*(double)yf + (double)RT[2])*dd + (double)RT[9];
        double py_ = ((double)RT[3]*(double)xf + (double)RT[4]*(double)yf + (double)RT[5])*dd + (double)RT[10];
        double pz_ = ((double)RT[6]*(double)xf + (double)RT[7]*(double)yf + (double)RT[8])*dd + (double)RT[11];
        if (pz_ == 0.0) pz_ = 1e-9;
        double iz = 1.0/pz_;
        double pxd = px_*iz, pyd = py_*iz;
        double x0d = floor(pxd), y0d = floor(pyd);
        int x0i = (int)x0d, y0i = (int)y0d;
        int x1i = x0i + 1,  y1i = y0i + 1;
        float wx = (float)(pxd - x0d), wy = (float)(pyd - y0d);
        float vx0 = (x0i >= 0 && x0i < NW) ? 1.f : 0.f;
        float vx1 = (x1i >= 0 && x1i < NW) ? 1.f : 0.f;
        float vy0 = (y0i >= 0 && y0i < NH) ? 1.f : 0.f;
        float vy1 = (y1i >= 0 && y1i < NH) ? 1.f : 0.f;
        float w00 = (1.f-wx)*(1.f-wy) * vx0*vy0;
        float w01 = wx*(1.f-wy)       * vx1*vy0;
        float w10 = (1.f-wx)*wy       * vx0*vy1;
        float w11 = wx*wy             * vx1*vy1;
        int xc0 = min(max(x0i,0),NW-1), xc1 = min(max(x1i,0),NW-1);
        int yc0 = min(max(y0i,0),NH-1), yc1 = min(max(y1i,0),NH-1);
        int i00 = yc0*NW+xc0, i01 = yc0*NW+xc1;
        int i10 = yc1*NW+xc0, i11 = yc1*NW+xc1;
        const float* sb = src_feats + ((v*NB + b)*NC)*HW;
        const float* rb = ref_feats + ((v*NB + b)*NC)*HW + h*NW + w;
        float acc[NG];
        #pragma unroll
        for (int g = 0; g < NG; ++g) acc[g] = 0.f;
        #pragma unroll
        for (int c = 0; c < NC; ++c) {
            const float* scp = sb + c*HW;
            float f = w00*scp[i00] + w01*scp[i01] + w10*scp[i10] + w11*scp[i11];
            acc[c>>2] += f * rb[c*HW];
        }
        float s = 0.f, t = 0.f;
        #pragma unroll
        for (int g = 0; g < NG; ++g) {
            float cf = 0.25f*acc[g];
            s += cf;
            t += cf*wr[g];
        }
        float m = s;
        #pragma unroll
        for (int mask = 1; mask < 32; mask <<= 1)
            m = fmaxf(m, __shfl_xor(m, mask, 32));
        float e = expf(s - m);
        float Z = e;
        #pragma unroll
        for (int mask = 1; mask < 32; mask <<= 1)
            Z += __shfl_xor(Z, mask, 32);
        float cw = 1.f / Z;
        logacc += cw * t;
        cwsum  += cw;
    }
    float logit = logacc / (cwsum + 1e-7f);
    float m2 = logit;
    #pragma unroll
    for (int mask = 1; mask < 32; mask <<= 1)
        m2 = fmaxf(m2, __shfl_xor(m2, mask, 32));
    float e2 = expf(logit - m2);
    float Z2 = e2;
    #pragma unroll
    for (int mask = 1; mask < 32; mask <<= 1)
        Z2 += __shfl_xor(Z2, mask, 32);
    float aw = e2 / Z2;
    out[NPIX + ((b*ND + d)*NH + h)*NW + w] = aw;
    float bv = aw; int bi = d;
    #pragma unroll
    for (int mask = 1; mask < 32; mask <<= 1) {
        float ov = __shfl_xor(bv, mask, 32);
        int   oi = __shfl_xor(bi, mask, 32);
        if (ov > bv || (ov == bv && oi < bi)) { bv = ov; bi = oi; }
    }
    float dsel = __shfl(depth, bi, 32);
    if (d == 0) out[p] = dsel;
}

extern "C" void kernel_launch(void* const* d_in, const int* in_sizes, int n_in,
                              void* d_out, int out_size, void* d_ws, size_t ws_size,
                              hipStream_t stream) {
    const float* ref_feats  = (const float*)d_in[0];
    const float* src_feats  = (const float*)d_in[1];
    const float* proj       = (const float*)d_in[2];
    const float* depth_hypo = (const float*)d_in[3];
    const float* w_reg      = (const float*)d_in[4];
    float* out = (float*)d_out;

    size_t featB = (size_t)FEATSZ*sizeof(float);               // 21.0 MB
    size_t geoN  = (size_t)NV*NPIX*ND;                         // 5.24M entries
    size_t needG = 2*featB + geoN*sizeof(float2) + geoN*4      // srcT,refT,geoW,geoXY
                 + (size_t)NV*NPIX*sizeof(int4) + 96*sizeof(float);
    size_t needT = 2*featB + 96*sizeof(float);

    if (ws_size >= needG) {
        char* base = (char*)d_ws;
        float* srcT = (float*)base;                 base += featB;
        float* refT = (float*)base;                 base += featB;
        float2* geoW = (float2*)base;               base += geoN*sizeof(float2);
        unsigned int* geoXY = (unsigned int*)base;  base += geoN*4;
        int4* bboxA = (int4*)base;                  base += (size_t)NV*NPIX*sizeof(int4);
        float* pw = (float*)base;
        hipLaunchKernelGGL(proj_setup_kernel, dim3(1), dim3(64), 0, stream, proj, pw);
        dim3 tg(HW/64, NV*NB);
        hipLaunchKernelGGL(transpose_kernel, tg, dim3(256), 0, stream, src_feats, srcT);
        hipLaunchKernelGGL(transpose_kernel, tg, dim3(256), 0, stream, ref_feats, refT);
        hipLaunchKernelGGL(geo_precompute_kernel, dim3((NV*NPIX*32)/256), dim3(256), 0, stream,
                           depth_hypo, pw, geoXY, geoW, bboxA);
        hipLaunchKernelGGL(mvs_kernel_g, dim3((NPIX*64)/256), dim3(256), 0, stream,
                           refT, srcT, depth_hypo, w_reg, geoXY, geoW, bboxA, out);
    } else if (ws_size >= needT) {
        float* srcT = (float*)d_ws;
        float* refT = srcT + FEATSZ;
        float* pw   = refT + FEATSZ;
        hipLaunchKernelGGL(proj_setup_kernel, dim3(1), dim3(64), 0, stream, proj, pw);
        dim3 tg(HW/64, NV*NB);
        hipLaunchKernelGGL(transpose_kernel, tg, dim3(256), 0, stream, src_feats, srcT);
        hipLaunchKernelGGL(transpose_kernel, tg, dim3(256), 0, stream, ref_feats, refT);
        hipLaunchKernelGGL(mvs_kernel_t, dim3((NPIX*64)/256), dim3(256), 0, stream,
                           refT, srcT, depth_hypo, w_reg, pw, out);
    } else {
        float* pw = (float*)d_ws;
        hipLaunchKernelGGL(proj_setup_kernel, dim3(1), dim3(64), 0, stream, proj, pw);
        hipLaunchKernelGGL(mvs_kernel, dim3((NPIX*ND)/256), dim3(256), 0, stream,
                           ref_feats, src_feats, depth_hypo, w_reg, pw, out);
    }
}